// Round 1
// 880.202 us; speedup vs baseline: 1.0124x; 1.0124x over previous
//
#include <hip/hip_runtime.h>

constexpr int F  = 32;
constexpr int V  = 10000;
constexpr int D  = 496;     // 124 float4
constexpr int H  = 1024;

// ---------------- Kernel 1: FM interaction (gather-heavy) -----------------
// One row per 128-thread block. Goal: maximum occupancy (8 waves/EU -> 32
// waves/CU) so the random 1984-B row gathers saturate HBM. VGPR budget 64:
// unroll 4 keeps ~16 regs of loads in flight + 8 accumulator regs.
__global__ __launch_bounds__(128, 8) void fm_kernel(
    const float* __restrict__ xv,   // [B,F]
    const int*   __restrict__ xi,   // [B,F]
    const float* __restrict__ emb,  // [F,V,D]
    const float* __restrict__ W2,   // [D+H,1]
    const float* __restrict__ b2,   // [1]
    float* __restrict__ out)        // [B]
{
    const int b = blockIdx.x;
    const int t = threadIdx.x;

    __shared__ float        s_xv[F];
    __shared__ const float* s_row[F];
    __shared__ float        s_wsum[2];

    if (t < F) {
        s_xv[t]  = xv[b * F + t];
        s_row[t] = emb + ((size_t)t * V + (size_t)xi[b * F + t]) * D;
    }
    __syncthreads();

    float acc = 0.0f;
    if (t < D / 4) {
        float4 s  = make_float4(0.f, 0.f, 0.f, 0.f);
        float4 ss = make_float4(0.f, 0.f, 0.f, 0.f);
        #pragma unroll 4
        for (int f = 0; f < F; ++f) {
            const float xf = s_xv[f];
            float4 v = *reinterpret_cast<const float4*>(s_row[f] + 4 * t);
            v.x *= xf; v.y *= xf; v.z *= xf; v.w *= xf;
            s.x  += v.x;       s.y  += v.y;       s.z  += v.z;       s.w  += v.w;
            ss.x += v.x * v.x; ss.y += v.y * v.y; ss.z += v.z * v.z; ss.w += v.w * v.w;
        }
        float4 w = *reinterpret_cast<const float4*>(W2 + 4 * t);
        acc = (0.5f * (s.x * s.x - ss.x)) * w.x
            + (0.5f * (s.y * s.y - ss.y)) * w.y
            + (0.5f * (s.z * s.z - ss.z)) * w.z
            + (0.5f * (s.w * s.w - ss.w)) * w.w;
    }

    #pragma unroll
    for (int off = 32; off > 0; off >>= 1)
        acc += __shfl_down(acc, off, 64);
    if ((t & 63) == 0) s_wsum[t >> 6] = acc;
    __syncthreads();
    if (t == 0) out[b] = s_wsum[0] + s_wsum[1] + b2[0];
}

// ---------------- Kernel 2: MLP branch (compute/L2-bound) -----------------
// 64 rows per 256-thread block. Each thread owns 4 H-columns; each W1 float4
// is loaded ONCE per (f, column-quad) and FMA'd against 8 rows held in
// registers. W1 demand traffic: 2.1 GB (old, per-row) -> 33 MB (per-64-rows).
constexpr int R  = 64;   // rows per block
constexpr int RC = 8;    // row chunk held in registers

__global__ __launch_bounds__(256, 4) void mlp_kernel(
    const float* __restrict__ xv,   // [B,F]
    const float* __restrict__ W1,   // [F,H]
    const float* __restrict__ b1,   // [H]
    const float* __restrict__ W2,   // [D+H,1]
    float* __restrict__ out,        // [B] (accumulates onto fm_kernel output)
    int B)
{
    const int t  = threadIdx.x;
    const int b0 = blockIdx.x * R;
    const int j0 = 4 * t;           // H-column base, 256*4 = 1024 = H

    __shared__ float s_xv[F][R];    // transposed tile: [field][row], 8 KB
    __shared__ float s_red[RC][4];

    // Coalesced global load of the 64x32 xv tile, transposed store to LDS.
    {
        const int r0 = t >> 3, f0 = 4 * (t & 7);
        const int rA = min(b0 + r0,      B - 1);
        const int rB = min(b0 + r0 + 32, B - 1);
        float4 v0 = *reinterpret_cast<const float4*>(xv + (size_t)rA * F + f0);
        float4 v1 = *reinterpret_cast<const float4*>(xv + (size_t)rB * F + f0);
        s_xv[f0 + 0][r0] = v0.x; s_xv[f0 + 1][r0] = v0.y;
        s_xv[f0 + 2][r0] = v0.z; s_xv[f0 + 3][r0] = v0.w;
        s_xv[f0 + 0][r0 + 32] = v1.x; s_xv[f0 + 1][r0 + 32] = v1.y;
        s_xv[f0 + 2][r0 + 32] = v1.z; s_xv[f0 + 3][r0 + 32] = v1.w;
    }
    __syncthreads();

    const float4 w2v = *reinterpret_cast<const float4*>(W2 + D + j0);
    const float4 bv  = *reinterpret_cast<const float4*>(b1 + j0);

    for (int rc = 0; rc < R; rc += RC) {
        float4 h[RC];
        #pragma unroll
        for (int r = 0; r < RC; ++r) h[r] = bv;

        #pragma unroll 4
        for (int f = 0; f < F; ++f) {
            const float4 w  = *reinterpret_cast<const float4*>(W1 + f * H + j0);
            const float4 xa = *reinterpret_cast<const float4*>(&s_xv[f][rc]);      // rows rc..rc+3 (broadcast)
            const float4 xb = *reinterpret_cast<const float4*>(&s_xv[f][rc + 4]);  // rows rc+4..rc+7
            const float xr[RC] = {xa.x, xa.y, xa.z, xa.w, xb.x, xb.y, xb.z, xb.w};
            #pragma unroll
            for (int r = 0; r < RC; ++r) {
                h[r].x += xr[r] * w.x; h[r].y += xr[r] * w.y;
                h[r].z += xr[r] * w.z; h[r].w += xr[r] * w.w;
            }
        }

        // relu + dot with W2[D:], then block-wide reduction per row
        #pragma unroll
        for (int r = 0; r < RC; ++r) {
            float p = fmaxf(h[r].x, 0.f) * w2v.x + fmaxf(h[r].y, 0.f) * w2v.y
                    + fmaxf(h[r].z, 0.f) * w2v.z + fmaxf(h[r].w, 0.f) * w2v.w;
            #pragma unroll
            for (int off = 32; off > 0; off >>= 1)
                p += __shfl_down(p, off, 64);
            if ((t & 63) == 0) s_red[r][t >> 6] = p;
        }
        __syncthreads();
        if (t < RC) {
            const int row = b0 + rc + t;
            if (row < B)
                out[row] += s_red[t][0] + s_red[t][1] + s_red[t][2] + s_red[t][3];
        }
        __syncthreads();   // protect s_red before next chunk
    }
}

extern "C" void kernel_launch(void* const* d_in, const int* in_sizes, int n_in,
                              void* d_out, int out_size, void* d_ws, size_t ws_size,
                              hipStream_t stream) {
    const float* xv  = (const float*)d_in[0];
    const int*   xi  = (const int*)d_in[1];
    const float* emb = (const float*)d_in[2];
    const float* W1  = (const float*)d_in[3];
    const float* b1  = (const float*)d_in[4];
    const float* W2  = (const float*)d_in[5];
    const float* b2  = (const float*)d_in[6];
    float* out = (float*)d_out;

    const int B = in_sizes[0] / F;

    // Kernel 1 writes out[b] = FM-part + b2; kernel 2 (same stream, ordered)
    // accumulates the MLP-part on top.
    fm_kernel<<<B, 128, 0, stream>>>(xv, xi, emb, W2, b2, out);
    mlp_kernel<<<(B + R - 1) / R, 256, 0, stream>>>(xv, W1, b1, W2, out, B);
}